// Round 1
// baseline (2205.185 us; speedup 1.0000x reference)
//
#include <hip/hip_runtime.h>
#include <cstdint>
#include <cstddef>

typedef __bf16 bf16_t;
typedef __bf16 bf16x8 __attribute__((ext_vector_type(8)));
typedef float f32x4 __attribute__((ext_vector_type(4)));

#define B_  4
#define N_  64
#define FP_ 256
#define TP_ 32
#define V_  32000
#define D_  1024
#define L_  2048
#define M_  8192   // B_*L_

// -------- async global->LDS (16B per lane, wave-uniform LDS base) --------
__device__ __forceinline__ void async_copy16(const void* g, void* l) {
  __builtin_amdgcn_global_load_lds(
      (__attribute__((address_space(1))) void*)g,
      (__attribute__((address_space(3))) void*)l,
      16, 0, 0);
}

// -------- zero rowsum --------
__global__ void k_zero(float* __restrict__ p, int n) {
  int i = blockIdx.x * 256 + threadIdx.x;
  if (i < n) p[i] = 0.0f;
}

// -------- x_prime (B,N,FP,TP) fp32 -> Xb (M, FP) bf16, m = b*L + t*N + n --------
__global__ void k_convert_x(const float* __restrict__ xp, bf16_t* __restrict__ Xb) {
  int idx = blockIdx.x * 256 + threadIdx.x;   // < M_*FP_
  int f = idx & 255;
  int m = idx >> 8;
  int b = m >> 11;
  int l = m & 2047;
  int t = l >> 6;
  int n = l & 63;
  float v = xp[(((size_t)(b * N_ + n) * FP_ + f) * TP_) + t];
  Xb[idx] = (bf16_t)v;
}

// -------- transpose+convert: src (R,C) fp32 -> dst (C,R) bf16 --------
// grid: (C/64, R/64), 256 threads
__global__ void k_transpose_cvt(const float* __restrict__ src, bf16_t* __restrict__ dst,
                                int R, int C) {
  __shared__ float tile[64][65];
  int ct = blockIdx.x;
  int rt = blockIdx.y;
  int tid = threadIdx.x;
#pragma unroll
  for (int i = 0; i < 16; i++) {
    int idx = tid + i * 256;
    int a = idx >> 6, bc = idx & 63;
    tile[a][bc] = src[(size_t)(rt * 64 + a) * C + ct * 64 + bc];
  }
  __syncthreads();
#pragma unroll
  for (int i = 0; i < 16; i++) {
    int idx = tid + i * 256;
    int a = idx >> 6, bc = idx & 63;
    dst[(size_t)(ct * 64 + a) * R + rt * 64 + bc] = (bf16_t)tile[bc][a];
  }
}

// ======== GEMM1: P[pr][v] = exp(X[m]·Wt[v] + bias[v]); rowsum[m] += sum_v ========
// A = Xb (M,256) bf16 k-contig; B^T = Wt (V,256) bf16 k-contig.
// 128x128 tile, BK=64, 256 threads (4 waves, 2x2 of 64x64), mfma 16x16x32 bf16.
__global__ __launch_bounds__(256) void k_gemm1(
    const bf16_t* __restrict__ Xb, const bf16_t* __restrict__ Wt,
    const float* __restrict__ bias, bf16_t* __restrict__ P,
    float* __restrict__ rowsum, int mbase) {
  __shared__ __align__(16) bf16_t As[128 * 64];
  __shared__ __align__(16) bf16_t Bs[128 * 64];

  const int tid = threadIdx.x;
  const int lane = tid & 63;
  const int wid = tid >> 6;
  const int wr = wid >> 1, wc = wid & 1;
  const int c16 = lane & 15, quad = lane >> 4;
  const int lrow = lane >> 3;                 // 0..7
  const int lchunk = (lane & 7) ^ lrow;       // xor-swizzled global 16B-chunk

  const int vtile = blockIdx.x;               // 0..249
  const int mtile = blockIdx.y;
  const int m0 = mbase + mtile * 128;         // global row base
  const int v0 = vtile * 128;

  f32x4 acc[4][4];
#pragma unroll
  for (int i = 0; i < 4; i++)
#pragma unroll
    for (int j = 0; j < 4; j++) acc[i][j] = (f32x4){0.f, 0.f, 0.f, 0.f};

  for (int kt = 0; kt < FP_; kt += 64) {
#pragma unroll
    for (int i = 0; i < 4; i++) {
      int r0 = (wid * 4 + i) * 8;
      int ra = r0 + lrow;
      async_copy16(Xb + (size_t)(m0 + ra) * FP_ + kt + lchunk * 8, &As[r0 * 64]);
      async_copy16(Wt + (size_t)(v0 + ra) * FP_ + kt + lchunk * 8, &Bs[r0 * 64]);
    }
    __syncthreads();
#pragma unroll
    for (int s = 0; s < 2; s++) {
      bf16x8 af[4], bfr[4];
      int g = s * 4 + quad;
#pragma unroll
      for (int i = 0; i < 4; i++) {
        int r = wr * 64 + i * 16 + c16;
        af[i] = *(const bf16x8*)&As[r * 64 + ((g ^ (r & 7)) << 3)];
        int rn = wc * 64 + i * 16 + c16;
        bfr[i] = *(const bf16x8*)&Bs[rn * 64 + ((g ^ (rn & 7)) << 3)];
      }
#pragma unroll
      for (int i = 0; i < 4; i++)
#pragma unroll
        for (int j = 0; j < 4; j++)
          acc[i][j] = __builtin_amdgcn_mfma_f32_16x16x32_bf16(af[i], bfr[j], acc[i][j], 0, 0, 0);
    }
    __syncthreads();
  }

  // epilogue: exp, store bf16 P, per-row sums via shuffle + atomicAdd
  float bv[4];
#pragma unroll
  for (int j = 0; j < 4; j++) bv[j] = bias[v0 + wc * 64 + j * 16 + c16];

#pragma unroll
  for (int i = 0; i < 4; i++) {
#pragma unroll
    for (int e = 0; e < 4; e++) {
      int rr = m0 + wr * 64 + i * 16 + quad * 4 + e;  // global row
      int pr = rr - mbase;                             // chunk-local row
      float s = 0.0f;
#pragma unroll
      for (int j = 0; j < 4; j++) {
        int v = v0 + wc * 64 + j * 16 + c16;
        float p = __expf(acc[i][j][e] + bv[j]);
        bf16_t pb = (bf16_t)p;
        P[(size_t)pr * V_ + v] = pb;
        s += (float)pb;   // sum what we actually stored
      }
#pragma unroll
      for (int off = 1; off < 16; off <<= 1) s += __shfl_xor(s, off, 16);
      if (c16 == 0) atomicAdd(&rowsum[rr], s);
    }
  }
}

// ======== GEMM2: H[m][d] = (sum_v P[pr][v]*Et[d][v]) / rowsum[m] ========
// A = P (chunk,V) bf16 k-contig; B^T = Et (D,V) bf16 k-contig.
__global__ __launch_bounds__(256) void k_gemm2(
    const bf16_t* __restrict__ P, const bf16_t* __restrict__ Et,
    const float* __restrict__ rowsum, float* __restrict__ H, int mbase) {
  __shared__ __align__(16) bf16_t As[128 * 64];
  __shared__ __align__(16) bf16_t Bs[128 * 64];

  const int tid = threadIdx.x;
  const int lane = tid & 63;
  const int wid = tid >> 6;
  const int wr = wid >> 1, wc = wid & 1;
  const int c16 = lane & 15, quad = lane >> 4;
  const int lrow = lane >> 3;
  const int lchunk = (lane & 7) ^ lrow;

  const int dtile = blockIdx.x;               // 0..7
  const int mtile = blockIdx.y;
  const int m0 = mbase + mtile * 128;
  const int prow0 = mtile * 128;              // chunk-local
  const int d0 = dtile * 128;

  f32x4 acc[4][4];
#pragma unroll
  for (int i = 0; i < 4; i++)
#pragma unroll
    for (int j = 0; j < 4; j++) acc[i][j] = (f32x4){0.f, 0.f, 0.f, 0.f};

  for (int kt = 0; kt < V_; kt += 64) {
#pragma unroll
    for (int i = 0; i < 4; i++) {
      int r0 = (wid * 4 + i) * 8;
      int ra = r0 + lrow;
      async_copy16(P + (size_t)(prow0 + ra) * V_ + kt + lchunk * 8, &As[r0 * 64]);
      async_copy16(Et + (size_t)(d0 + ra) * V_ + kt + lchunk * 8, &Bs[r0 * 64]);
    }
    __syncthreads();
#pragma unroll
    for (int s = 0; s < 2; s++) {
      bf16x8 af[4], bfr[4];
      int g = s * 4 + quad;
#pragma unroll
      for (int i = 0; i < 4; i++) {
        int r = wr * 64 + i * 16 + c16;
        af[i] = *(const bf16x8*)&As[r * 64 + ((g ^ (r & 7)) << 3)];
        int rn = wc * 64 + i * 16 + c16;
        bfr[i] = *(const bf16x8*)&Bs[rn * 64 + ((g ^ (rn & 7)) << 3)];
      }
#pragma unroll
      for (int i = 0; i < 4; i++)
#pragma unroll
        for (int j = 0; j < 4; j++)
          acc[i][j] = __builtin_amdgcn_mfma_f32_16x16x32_bf16(af[i], bfr[j], acc[i][j], 0, 0, 0);
    }
    __syncthreads();
  }

#pragma unroll
  for (int i = 0; i < 4; i++) {
#pragma unroll
    for (int e = 0; e < 4; e++) {
      int rr = m0 + wr * 64 + i * 16 + quad * 4 + e;
      float inv = 1.0f / rowsum[rr];
#pragma unroll
      for (int j = 0; j < 4; j++) {
        int d = d0 + wc * 64 + j * 16 + c16;
        H[(size_t)rr * D_ + d] = acc[i][j][e] * inv;
      }
    }
  }
}

// ======== host ========
extern "C" void kernel_launch(void* const* d_in, const int* in_sizes, int n_in,
                              void* d_out, int out_size, void* d_ws, size_t ws_size,
                              hipStream_t stream) {
  const float* xp   = (const float*)d_in[0];   // (B,N,FP,TP)
  const float* E    = (const float*)d_in[1];   // (V,D)
  const float* W    = (const float*)d_in[2];   // (FP,V)
  const float* bias = (const float*)d_in[3];   // (V)
  float* out = (float*)d_out;                  // (M,D)

  char* ws = (char*)d_ws;
  const size_t szXb = (size_t)M_ * FP_ * 2;        // 4,194,304
  const size_t szWt = (size_t)V_ * FP_ * 2;        // 16,384,000
  const size_t szEt = (size_t)D_ * V_ * 2;         // 65,536,000
  const size_t szRs = (size_t)M_ * 4;              // 32,768
  bf16_t* Xb = (bf16_t*)ws;
  bf16_t* Wt = (bf16_t*)(ws + szXb);
  bf16_t* Et = (bf16_t*)(ws + szXb + szWt);
  float* rowsum = (float*)(ws + szXb + szWt + szEt);
  bf16_t* P = (bf16_t*)(ws + szXb + szWt + szEt + szRs);

  const size_t fixed = szXb + szWt + szEt + szRs;
  size_t avail = (ws_size > fixed) ? (ws_size - fixed) : 0;
  long maxrows = (long)(avail / ((size_t)V_ * 2));
  maxrows = (maxrows / 128) * 128;
  if (maxrows > M_) maxrows = M_;
  if (maxrows < 128) maxrows = 128;  // below this ws is insufficient anyway
  const int chunk = (int)maxrows;

  k_zero<<<(M_ + 255) / 256, 256, 0, stream>>>(rowsum, M_);
  k_convert_x<<<(M_ * FP_) / 256, 256, 0, stream>>>(xp, Xb);
  {
    dim3 g(V_ / 64, FP_ / 64);   // (500, 4)
    k_transpose_cvt<<<g, 256, 0, stream>>>(W, Wt, FP_, V_);
  }
  {
    dim3 g(D_ / 64, V_ / 64);    // (16, 500)
    k_transpose_cvt<<<g, 256, 0, stream>>>(E, Et, V_, D_);
  }

  for (int mb = 0; mb < M_; mb += chunk) {
    int rows = M_ - mb;
    if (rows > chunk) rows = chunk;
    dim3 g1(V_ / 128, rows / 128);   // (250, rows/128)
    k_gemm1<<<g1, 256, 0, stream>>>(Xb, Wt, bias, P, rowsum, mb);
    dim3 g2(D_ / 128, rows / 128);   // (8, rows/128)
    k_gemm2<<<g2, 256, 0, stream>>>(P, Et, rowsum, out, mb);
  }
}

// Round 2
// 1946.578 us; speedup vs baseline: 1.1329x; 1.1329x over previous
//
#include <hip/hip_runtime.h>
#include <cstdint>
#include <cstddef>

typedef __bf16 bf16_t;
typedef __bf16 bf16x8 __attribute__((ext_vector_type(8)));
typedef float f32x4 __attribute__((ext_vector_type(4)));

#define B_  4
#define N_  64
#define FP_ 256
#define TP_ 32
#define V_  32000
#define D_  1024
#define L_  2048
#define M_  8192   // B_*L_
#define VHALF_ 16000

// -------- async global->LDS (16B per lane, wave-uniform LDS base) --------
__device__ __forceinline__ void async_copy16(const void* g, void* l) {
  __builtin_amdgcn_global_load_lds(
      (__attribute__((address_space(1))) void*)g,
      (__attribute__((address_space(3))) void*)l,
      16, 0, 0);
}

// -------- zero helpers --------
__global__ void k_zero(float* __restrict__ p, int n) {
  int i = blockIdx.x * 256 + threadIdx.x;
  if (i < n) p[i] = 0.0f;
}
__global__ void k_zero4(float* __restrict__ p) {   // grid covers n/4 exactly
  int i = blockIdx.x * 256 + threadIdx.x;
  ((f32x4*)p)[i] = (f32x4){0.f, 0.f, 0.f, 0.f};
}

// -------- x_prime (B,N,FP,TP) fp32 -> Xb (M,FP) bf16, m = b*L + t*N + n --------
// one block per (b,n): reads (256 f x 32 t) coalesced, LDS-transposes,
// writes 32 rows of 256 contiguous bf16.
__global__ __launch_bounds__(256) void k_convert_x(const float* __restrict__ xp,
                                                   bf16_t* __restrict__ Xb) {
  __shared__ float tile[256][33];
  const int tid = threadIdx.x;
  const int b = blockIdx.x >> 6;
  const int n = blockIdx.x & 63;
  const float* src = xp + (size_t)(b * N_ + n) * FP_ * TP_;   // (f,t) 256x32
#pragma unroll
  for (int i = 0; i < 32; i++) {
    int idx = i * 256 + tid;
    tile[idx >> 5][idx & 31] = src[idx];
  }
  __syncthreads();
#pragma unroll
  for (int t = 0; t < 32; t++) {
    Xb[(size_t)(b * L_ + t * N_ + n) * FP_ + tid] = (bf16_t)tile[tid][t];
  }
}

// -------- transpose+convert: src (R,C) fp32 -> dst (C,R) bf16 --------
__global__ void k_transpose_cvt(const float* __restrict__ src, bf16_t* __restrict__ dst,
                                int R, int C) {
  __shared__ float tile[64][65];
  int ct = blockIdx.x;
  int rt = blockIdx.y;
  int tid = threadIdx.x;
#pragma unroll
  for (int i = 0; i < 16; i++) {
    int idx = tid + i * 256;
    int a = idx >> 6, bc = idx & 63;
    tile[a][bc] = src[(size_t)(rt * 64 + a) * C + ct * 64 + bc];
  }
  __syncthreads();
#pragma unroll
  for (int i = 0; i < 16; i++) {
    int idx = tid + i * 256;
    int a = idx >> 6, bc = idx & 63;
    dst[(size_t)(ct * 64 + a) * R + rt * 64 + bc] = (bf16_t)tile[bc][a];
  }
}

// ======== GEMM1: P[pr][v] = exp(X[m]·Wt[v] + bias[v]); rowsum[m] += sum_v ========
__global__ __launch_bounds__(256) void k_gemm1(
    const bf16_t* __restrict__ Xb, const bf16_t* __restrict__ Wt,
    const float* __restrict__ bias, bf16_t* __restrict__ P,
    float* __restrict__ rowsum, int mbase) {
  __shared__ __align__(16) bf16_t As[128 * 64];
  __shared__ __align__(16) bf16_t Bs[128 * 64];

  const int tid = threadIdx.x;
  const int lane = tid & 63;
  const int wid = tid >> 6;
  const int wr = wid >> 1, wc = wid & 1;
  const int c16 = lane & 15, quad = lane >> 4;
  const int lrow = lane >> 3;
  const int lchunk = (lane & 7) ^ lrow;

  const int vtile = blockIdx.x;
  const int mtile = blockIdx.y;
  const int m0 = mbase + mtile * 128;
  const int v0 = vtile * 128;

  f32x4 acc[4][4];
#pragma unroll
  for (int i = 0; i < 4; i++)
#pragma unroll
    for (int j = 0; j < 4; j++) acc[i][j] = (f32x4){0.f, 0.f, 0.f, 0.f};

  for (int kt = 0; kt < FP_; kt += 64) {
#pragma unroll
    for (int i = 0; i < 4; i++) {
      int r0 = (wid * 4 + i) * 8;
      int ra = r0 + lrow;
      async_copy16(Xb + (size_t)(m0 + ra) * FP_ + kt + lchunk * 8, &As[r0 * 64]);
      async_copy16(Wt + (size_t)(v0 + ra) * FP_ + kt + lchunk * 8, &Bs[r0 * 64]);
    }
    __syncthreads();
#pragma unroll
    for (int s = 0; s < 2; s++) {
      bf16x8 af[4], bfr[4];
      int g = s * 4 + quad;
#pragma unroll
      for (int i = 0; i < 4; i++) {
        int r = wr * 64 + i * 16 + c16;
        af[i] = *(const bf16x8*)&As[r * 64 + ((g ^ (r & 7)) << 3)];
        int rn = wc * 64 + i * 16 + c16;
        bfr[i] = *(const bf16x8*)&Bs[rn * 64 + ((g ^ (rn & 7)) << 3)];
      }
#pragma unroll
      for (int i = 0; i < 4; i++)
#pragma unroll
        for (int j = 0; j < 4; j++)
          acc[i][j] = __builtin_amdgcn_mfma_f32_16x16x32_bf16(af[i], bfr[j], acc[i][j], 0, 0, 0);
    }
    __syncthreads();
  }

  float bv[4];
#pragma unroll
  for (int j = 0; j < 4; j++) bv[j] = bias[v0 + wc * 64 + j * 16 + c16];

#pragma unroll
  for (int i = 0; i < 4; i++) {
#pragma unroll
    for (int e = 0; e < 4; e++) {
      int rr = m0 + wr * 64 + i * 16 + quad * 4 + e;
      int pr = rr - mbase;
      float s = 0.0f;
#pragma unroll
      for (int j = 0; j < 4; j++) {
        int v = v0 + wc * 64 + j * 16 + c16;
        float p = __expf(acc[i][j][e] + bv[j]);
        bf16_t pb = (bf16_t)p;
        P[(size_t)pr * V_ + v] = pb;
        s += (float)pb;
      }
#pragma unroll
      for (int off = 1; off < 16; off <<= 1) s += __shfl_xor(s, off, 16);
      if (c16 == 0) atomicAdd(&rowsum[rr], s);
    }
  }
}

// ======== GEMM2 (split-K=2): partial[m][d] = sum_{v in slice} P[pr][v]*Et[d][v] ========
// ATOMIC=false: dst is partial buffer base, slice z writes dst + z*M*D (plain store)
// ATOMIC=true : dst is out (pre-zeroed), atomicAdd
template <bool ATOMIC>
__global__ __launch_bounds__(256) void k_gemm2(
    const bf16_t* __restrict__ P, const bf16_t* __restrict__ Et,
    float* __restrict__ dst, int mbase) {
  __shared__ __align__(16) bf16_t As[128 * 64];
  __shared__ __align__(16) bf16_t Bs[128 * 64];

  const int tid = threadIdx.x;
  const int lane = tid & 63;
  const int wid = tid >> 6;
  const int wr = wid >> 1, wc = wid & 1;
  const int c16 = lane & 15, quad = lane >> 4;
  const int lrow = lane >> 3;
  const int lchunk = (lane & 7) ^ lrow;

  const int dtile = blockIdx.x;               // 0..7
  const int mtile = blockIdx.y;
  const int kslice = blockIdx.z;              // 0..1
  const int kbase = kslice * VHALF_;
  const int m0 = mbase + mtile * 128;
  const int prow0 = mtile * 128;
  const int d0 = dtile * 128;
  float* __restrict__ o = ATOMIC ? dst : dst + (size_t)kslice * M_ * D_;

  f32x4 acc[4][4];
#pragma unroll
  for (int i = 0; i < 4; i++)
#pragma unroll
    for (int j = 0; j < 4; j++) acc[i][j] = (f32x4){0.f, 0.f, 0.f, 0.f};

  for (int kt = kbase; kt < kbase + VHALF_; kt += 64) {
#pragma unroll
    for (int i = 0; i < 4; i++) {
      int r0 = (wid * 4 + i) * 8;
      int ra = r0 + lrow;
      async_copy16(P + (size_t)(prow0 + ra) * V_ + kt + lchunk * 8, &As[r0 * 64]);
      async_copy16(Et + (size_t)(d0 + ra) * V_ + kt + lchunk * 8, &Bs[r0 * 64]);
    }
    __syncthreads();
#pragma unroll
    for (int s = 0; s < 2; s++) {
      bf16x8 af[4], bfr[4];
      int g = s * 4 + quad;
#pragma unroll
      for (int i = 0; i < 4; i++) {
        int r = wr * 64 + i * 16 + c16;
        af[i] = *(const bf16x8*)&As[r * 64 + ((g ^ (r & 7)) << 3)];
        int rn = wc * 64 + i * 16 + c16;
        bfr[i] = *(const bf16x8*)&Bs[rn * 64 + ((g ^ (rn & 7)) << 3)];
      }
#pragma unroll
      for (int i = 0; i < 4; i++)
#pragma unroll
        for (int j = 0; j < 4; j++)
          acc[i][j] = __builtin_amdgcn_mfma_f32_16x16x32_bf16(af[i], bfr[j], acc[i][j], 0, 0, 0);
    }
    __syncthreads();
  }

#pragma unroll
  for (int i = 0; i < 4; i++) {
#pragma unroll
    for (int e = 0; e < 4; e++) {
      int rr = m0 + wr * 64 + i * 16 + quad * 4 + e;
#pragma unroll
      for (int j = 0; j < 4; j++) {
        int d = d0 + wc * 64 + j * 16 + c16;
        if (ATOMIC)
          atomicAdd(&o[(size_t)rr * D_ + d], acc[i][j][e]);
        else
          o[(size_t)rr * D_ + d] = acc[i][j][e];
      }
    }
  }
}

// -------- finalize --------
__global__ void k_finalize_part(const float* __restrict__ p0, const float* __restrict__ p1,
                                const float* __restrict__ rowsum, float* __restrict__ out) {
  int i = blockIdx.x * 256 + threadIdx.x;     // over M*D/4
  int row = (i * 4) >> 10;                    // /D_
  float inv = 1.0f / rowsum[row];
  f32x4 a = ((const f32x4*)p0)[i];
  f32x4 b = ((const f32x4*)p1)[i];
  f32x4 r;
  r.x = (a.x + b.x) * inv; r.y = (a.y + b.y) * inv;
  r.z = (a.z + b.z) * inv; r.w = (a.w + b.w) * inv;
  ((f32x4*)out)[i] = r;
}
__global__ void k_normalize(float* __restrict__ out, const float* __restrict__ rowsum) {
  int i = blockIdx.x * 256 + threadIdx.x;
  int row = (i * 4) >> 10;
  float inv = 1.0f / rowsum[row];
  f32x4 a = ((f32x4*)out)[i];
  a.x *= inv; a.y *= inv; a.z *= inv; a.w *= inv;
  ((f32x4*)out)[i] = a;
}

// ======== host ========
extern "C" void kernel_launch(void* const* d_in, const int* in_sizes, int n_in,
                              void* d_out, int out_size, void* d_ws, size_t ws_size,
                              hipStream_t stream) {
  const float* xp   = (const float*)d_in[0];   // (B,N,FP,TP)
  const float* E    = (const float*)d_in[1];   // (V,D)
  const float* W    = (const float*)d_in[2];   // (FP,V)
  const float* bias = (const float*)d_in[3];   // (V)
  float* out = (float*)d_out;                  // (M,D)

  char* ws = (char*)d_ws;
  const size_t szXb = (size_t)M_ * FP_ * 2;
  const size_t szWt = (size_t)V_ * FP_ * 2;
  const size_t szEt = (size_t)D_ * V_ * 2;
  const size_t szRs = (size_t)M_ * 4;
  bf16_t* Xb = (bf16_t*)ws;
  bf16_t* Wt = (bf16_t*)(ws + szXb);
  bf16_t* Et = (bf16_t*)(ws + szXb + szWt);
  float* rowsum = (float*)(ws + szXb + szWt + szEt);
  bf16_t* P = (bf16_t*)(ws + szXb + szWt + szEt + szRs);

  const size_t fixed = szXb + szWt + szEt + szRs;
  const size_t szP = (size_t)M_ * V_ * 2;
  const size_t szPart = (size_t)2 * M_ * D_ * 4;   // two fp32 partial slices

  // P chunking (degrades gracefully if ws is small)
  size_t avail = (ws_size > fixed) ? (ws_size - fixed) : 0;
  bool partials_fit = (avail >= szP + szPart);
  size_t avail_p = partials_fit ? (avail - szPart) : avail;
  long maxrows = (long)(avail_p / ((size_t)V_ * 2));
  maxrows = (maxrows / 128) * 128;
  if (maxrows > M_) maxrows = M_;
  if (maxrows < 128) maxrows = 128;
  const int chunk = (int)maxrows;
  float* partial = (float*)(ws + fixed + (size_t)chunk * V_ * 2);

  k_zero<<<(M_ + 255) / 256, 256, 0, stream>>>(rowsum, M_);
  if (!partials_fit) {
    k_zero4<<<(M_ * D_ / 4) / 256, 256, 0, stream>>>(out);
  }
  k_convert_x<<<B_ * N_, 256, 0, stream>>>(xp, Xb);
  {
    dim3 g(V_ / 64, FP_ / 64);
    k_transpose_cvt<<<g, 256, 0, stream>>>(W, Wt, FP_, V_);
  }
  {
    dim3 g(D_ / 64, V_ / 64);
    k_transpose_cvt<<<g, 256, 0, stream>>>(E, Et, V_, D_);
  }

  for (int mb = 0; mb < M_; mb += chunk) {
    int rows = M_ - mb;
    if (rows > chunk) rows = chunk;
    dim3 g1(V_ / 128, rows / 128);
    k_gemm1<<<g1, 256, 0, stream>>>(Xb, Wt, bias, P, rowsum, mb);
    dim3 g2(D_ / 128, rows / 128, 2);
    if (partials_fit)
      k_gemm2<false><<<g2, 256, 0, stream>>>(P, Et, partial, mb);
    else
      k_gemm2<true><<<g2, 256, 0, stream>>>(P, Et, out, mb);
  }

  if (partials_fit) {
    k_finalize_part<<<(M_ * D_ / 4) / 256, 256, 0, stream>>>(
        partial, partial + (size_t)M_ * D_, rowsum, out);
  } else {
    k_normalize<<<(M_ * D_ / 4) / 256, 256, 0, stream>>>(out, rowsum);
  }
}